// Round 21
// baseline (247.315 us; speedup 1.0000x reference)
//
#include <hip/hip_runtime.h>

// ResidualNetwork forward, MI355X (gfx950).
// Round 21: r20 (fused 24-MFMA chain, 146.5us) with ONE variable flipped:
// the resident zero srcC is pinned into AGPRs ("+a") instead of VGPRs.
// r20 decomposition: VALU ~1030 instr/tile = 384 srcC v->a copies (16 x 24
// MFMA; intrinsic MFMA places srcC/D in AGPRs, my zero was VGPR-pinned)
// + 176 accvgpr_read (rc) + 176 rc packs + staging. AGPR-resident zero ->
// srcC consumed directly, copies vanish; D stays AGPR; rc pays only its
// 8 reads + 8 packs. Expected VALU/tile ~450 instr (~900 cyc).
// Chain unchanged (r20): 32x32x16_f16, fused A=[W1|W2] + W3-accumulate
// (24 MFMA/tile), sigma-permuted K, ones-row bias, ILP=2, lb(256,2).
// Gates: VALUBusy 75->50-62% (copy-term signature); MfmaUtil ~35-42%;
// FETCH ~24.8MB; WRITE 16384KB; absmax passes (bit-identical math).

#define NPTS 4194304
#define NBLK 2048
#define NWAVES (NBLK * 4)           // 8192
#define NTILES (NPTS / 32)          // 131072
#define TPW (NTILES / NWAVES)       // 16 tiles per wave
#define NMM 24
#define ILP 2

typedef _Float16 h8 __attribute__((ext_vector_type(8)));
typedef float v8f __attribute__((ext_vector_type(8)));
typedef float v16f __attribute__((ext_vector_type(16)));
typedef unsigned u4v __attribute__((ext_vector_type(4)));

__device__ __forceinline__ v16f mm(h8 a, h8 b, v16f c) {
    return __builtin_amdgcn_mfma_f32_32x32x16_f16(a, b, c, 0, 0, 0);
}
__device__ __forceinline__ unsigned pkrtz(float a, float b) {
    return __builtin_bit_cast(unsigned, __builtin_amdgcn_cvt_pkrtz(a, b));
}
// relu+pack of D regs 0-7 (rows sigma(k)): B fragment, sigma order
__device__ __forceinline__ h8 rc_lo(v16f d) {
    v8f s = __builtin_shufflevector(d, d, 0, 1, 2, 3, 4, 5, 6, 7);
    v8f z = {0.f, 0.f, 0.f, 0.f, 0.f, 0.f, 0.f, 0.f};
    v8f m = __builtin_elementwise_max(s, z);
    u4v u;
    u.x = pkrtz(m[0], m[1]); u.y = pkrtz(m[2], m[3]);
    u.z = pkrtz(m[4], m[5]); u.w = pkrtz(m[6], m[7]);
    return __builtin_bit_cast(h8, u);
}
// relu+pack of D regs 8-15 (rows 16+sigma(k)): same sigma order
__device__ __forceinline__ h8 rc_hi(v16f d) {
    v8f s = __builtin_shufflevector(d, d, 8, 9, 10, 11, 12, 13, 14, 15);
    v8f z = {0.f, 0.f, 0.f, 0.f, 0.f, 0.f, 0.f, 0.f};
    v8f m = __builtin_elementwise_max(s, z);
    u4v u;
    u.x = pkrtz(m[0], m[1]); u.y = pkrtz(m[2], m[3]);
    u.z = pkrtz(m[4], m[5]); u.w = pkrtz(m[6], m[7]);
    return __builtin_bit_cast(h8, u);
}

// ---------------- prepack: fused A fragments, sigma-permuted K ---------------
// q=0: layer0   q=1: layer1 dense   q=2+2l: fused [W1 rows0-10 | W2 rows16-26,
// ones-pass A[26][10]]   q=3+2l: W3 rows16-25   q=22: layer8   q=23: out row
__global__ __launch_bounds__(64) void prepack(
    const float* __restrict__ w0, const float* __restrict__ b0,
    const float* __restrict__ w1, const float* __restrict__ b1,
    const float* __restrict__ Wr1, const float* __restrict__ Br1,
    const float* __restrict__ Wr2, const float* __restrict__ Br2,
    const float* __restrict__ Wr3, const float* __restrict__ Br3,
    const float* __restrict__ w8, const float* __restrict__ b8,
    const float* __restrict__ w9, const float* __restrict__ b9,
    h8* __restrict__ tab)
{
    const int q = blockIdx.x, l = threadIdx.x;
    const int m = l & 31, g = l >> 5;
    h8 v;
#pragma unroll
    for (int j = 0; j < 8; ++j) {
        const int rr = (j & 3) + 8 * (j >> 2) + 4 * g;  // sigma(k)
        float a = 0.0f;
        if (q == 0) {
            if (m < 10 && rr < 3)        a = w0[rr * 10 + m];
            else if (m < 10 && rr == 3)  a = b0[m];
            else if (m == 10 && rr == 3) a = 1.0f;
        } else if (q == 1 || q == 22) {
            const float* W = (q == 1) ? w1 : w8;
            const float* B = (q == 1) ? b1 : b8;
            if (m < 10 && rr < 10)        a = W[rr * 10 + m];
            else if (m < 10 && rr == 10)  a = B[m];
            else if (m == 10 && rr == 10) a = 1.0f;
        } else if (q == 23) {
            if (m == 0 && rr < 10)       a = w9[rr];
            else if (m == 0 && rr == 10) a = b9[0];
        } else if (((q - 2) & 1) == 0) {           // fused W1|W2 block
            const int bl = (q - 2) >> 1;
            if (m < 10) {
                if (rr < 10)       a = Wr1[bl * 100 + rr * 10 + m];
                else if (rr == 10) a = Br1[bl * 10 + m];
            } else if (m >= 16 && m < 26) {
                if (rr < 10)       a = Wr2[bl * 100 + rr * 10 + (m - 16)];
                else if (rr == 10) a = Br2[bl * 10 + (m - 16)] + Br3[bl * 10 + (m - 16)];
            } else if (m == 26 && rr == 10) {
                a = 1.0f;                          // ones pass for next layer
            }
        } else {                                   // W3, output rows 16-25
            const int bl = (q - 3) >> 1;
            if (m >= 16 && m < 26 && rr < 10)
                a = Wr3[bl * 100 + rr * 10 + (m - 16)];
        }
        v[j] = (_Float16)a;
    }
    tab[q * 64 + l] = v;
}

// ---------------- main kernel: fused chain, AGPR-resident zero srcC ----------
__global__ __launch_bounds__(256, 2) void resnet_fwd(
    const float* __restrict__ x,
    const h8* __restrict__ tab,
    float* __restrict__ out)
{
    const int lane = threadIdx.x & 63;
    const int wv = blockIdx.x * 4 + (threadIdx.x >> 6);
    const int col = lane & 31;
    const bool lo = lane < 32;

    // weight fragments (24 x 16B/lane); allocator free to keep or remat
    h8 wA[NMM];
#pragma unroll
    for (int q = 0; q < NMM; ++q) wA[q] = tab[q * 64 + lane];

    // THE variable: zero srcC resident in AGPRs — matches the class the
    // intrinsic MFMA assigns to srcC/D, so no per-MFMA v->a copies.
    v16f zero;
#pragma unroll
    for (int j = 0; j < 16; ++j) zero[j] = 0.0f;
    asm volatile("" : "+a"(zero));

    const long tile0 = (long)wv * TPW;

    for (int t = 0; t < TPW; t += ILP) {
        long base[ILP];
        h8 hh[ILP];

        // layer-0 B: lanes 0-31 carry (x0,x1,x2,1) in k-rows 0-3; rest zero
#pragma unroll
        for (int c = 0; c < ILP; ++c) {
            base[c] = (tile0 + t + c) * 32;
            float a0 = 0.f, a1 = 0.f, a2 = 0.f, a3 = 0.f;
            if (lo) {
                const float* p = x + (base[c] + col) * 3;
                a0 = p[0]; a1 = p[1]; a2 = p[2]; a3 = 1.0f;
            }
            u4v u;
            u.x = pkrtz(a0, a1); u.y = pkrtz(a2, a3); u.z = 0u; u.w = 0u;
            hh[c] = __builtin_bit_cast(h8, u);
        }

        // layer 0, layer 1
#pragma unroll
        for (int c = 0; c < ILP; ++c) hh[c] = rc_lo(mm(wA[0], hh[c], zero));
#pragma unroll
        for (int c = 0; c < ILP; ++c) hh[c] = rc_lo(mm(wA[1], hh[c], zero));

        // residual blocks: 2 MFMA each (fused W1|W2, then W3 onto rows 16-26)
#pragma unroll
        for (int bl = 0; bl < 10; ++bl) {
            v16f d12[ILP];
#pragma unroll
            for (int c = 0; c < ILP; ++c) d12[c] = mm(wA[2 + 2 * bl], hh[c], zero);
#pragma unroll
            for (int c = 0; c < ILP; ++c) {
                h8 t1 = rc_lo(d12[c]);
                d12[c] = mm(wA[3 + 2 * bl], t1, d12[c]);
            }
#pragma unroll
            for (int c = 0; c < ILP; ++c) hh[c] = rc_hi(d12[c]);
        }

        // layer 8
#pragma unroll
        for (int c = 0; c < ILP; ++c) hh[c] = rc_lo(mm(wA[22], hh[c], zero));

        // output layer: D row 0 (lanes 0-31, reg 0) = result for 32 points
#pragma unroll
        for (int c = 0; c < ILP; ++c) {
            v16f d = mm(wA[23], hh[c], zero);
            if (lo) out[base[c] + col] = d[0];
        }
    }
}

extern "C" void kernel_launch(void* const* d_in, const int* in_sizes, int n_in,
                              void* d_out, int out_size, void* d_ws, size_t ws_size,
                              hipStream_t stream)
{
    const float* x   = (const float*)d_in[0];
    const float* w0  = (const float*)d_in[1];
    const float* b0  = (const float*)d_in[2];
    const float* w1  = (const float*)d_in[3];
    const float* b1  = (const float*)d_in[4];
    const float* Wr1 = (const float*)d_in[5];
    const float* Br1 = (const float*)d_in[6];
    const float* Wr2 = (const float*)d_in[7];
    const float* Br2 = (const float*)d_in[8];
    const float* Wr3 = (const float*)d_in[9];
    const float* Br3 = (const float*)d_in[10];
    const float* w8  = (const float*)d_in[11];
    const float* b8  = (const float*)d_in[12];
    const float* w9  = (const float*)d_in[13];
    const float* b9  = (const float*)d_in[14];
    float* out = (float*)d_out;
    h8* tab = (h8*)d_ws;   // 24 * 64 * 16B = 24.6 KB scratch

    hipLaunchKernelGGL(prepack, dim3(NMM), dim3(64), 0, stream,
                       w0, b0, w1, b1, Wr1, Br1, Wr2, Br2, Wr3, Br3,
                       w8, b8, w9, b9, tab);

    hipLaunchKernelGGL(resnet_fwd, dim3(NBLK), dim3(256), 0, stream,
                       x, (const h8*)tab, out);
}